// Round 1
// baseline (505.917 us; speedup 1.0000x reference)
//
#include <hip/hip_runtime.h>
#include <hip/hip_fp16.h>

typedef unsigned int uint32;

#define B_ 16
#define N_ 400
#define D_ 256
#define H_ 8
#define DH_ 32
#define NW_ 4

#if __has_builtin(__builtin_amdgcn_exp2f)
#define EXP2(x) __builtin_amdgcn_exp2f(x)
#else
#define EXP2(x) exp2f(x)
#endif

// log2(e)/sqrt(32): exp(|qk/sqrt(32) * w|) == exp2(|qk*SCL * w|)
#define QK_SCL 0.2550348f

using bf16x8 = __attribute__((ext_vector_type(8))) short;
using f32x4  = __attribute__((ext_vector_type(4))) float;

__device__ __forceinline__ ushort f2b(float f) {
  uint32 u = __float_as_uint(f);
  uint32 r = (u + 0x7fffu + ((u >> 16) & 1u)) >> 16;
  return (ushort)r;
}
__device__ __forceinline__ float b2f(ushort u) {
  return __uint_as_float(((uint32)u) << 16);
}
__device__ __forceinline__ void unpack2(uint32 u, float* o) {
  o[0] = __uint_as_float(u << 16);
  o[1] = __uint_as_float(u & 0xffff0000u);
}

// ---------------------------------------------------------------------------
// Convert fp32 inputs -> bf16 scratch copies (x + 6 weight matrices)
// ---------------------------------------------------------------------------
__global__ __launch_bounds__(256) void convert_kernel(
    const float* __restrict__ x,  const float* __restrict__ wq,
    const float* __restrict__ wk, const float* __restrict__ wv,
    const float* __restrict__ wo, const float* __restrict__ w1,
    const float* __restrict__ w2,
    ushort* __restrict__ xb,  ushort* __restrict__ wqb,
    ushort* __restrict__ wkb, ushort* __restrict__ wvb,
    ushort* __restrict__ wob, ushort* __restrict__ w1b,
    ushort* __restrict__ w2b) {
  int gid = blockIdx.x * 256 + threadIdx.x;   // unit = 4 floats
  const float* src; ushort* dst;
  if      (gid < 409600) { src = x;  dst = xb;  }
  else if ((gid -= 409600) < 16384) { src = wq; dst = wqb; }
  else if ((gid -= 16384) < 16384)  { src = wk; dst = wkb; }
  else if ((gid -= 16384) < 16384)  { src = wv; dst = wvb; }
  else if ((gid -= 16384) < 16384)  { src = wo; dst = wob; }
  else if ((gid -= 16384) < 65536)  { src = w1; dst = w1b; }
  else { gid -= 65536; src = w2; dst = w2b; }
  float4 f = ((const float4*)src)[gid];
  ushort4 u;
  u.x = f2b(f.x); u.y = f2b(f.y); u.z = f2b(f.z); u.w = f2b(f.w);
  *(ushort4*)&dst[(size_t)gid * 4] = u;
}

// ---------------------------------------------------------------------------
// Generic bf16 MFMA GEMM: C[M,N] = A[M,K] @ W[N,K]^T + bias, fused epilogue.
// 64x64 tile, 256 threads (4 waves), K-step 32, mfma_f32_16x16x32_bf16.
// ---------------------------------------------------------------------------
template <int RELU, int RESID, int OUT_F32, int OUT_BF16>
__global__ __launch_bounds__(256) void gemm_bt(
    const ushort* __restrict__ A, const ushort* __restrict__ W,
    const float* __restrict__ bias, const float* __restrict__ resid,
    float* __restrict__ outf, ushort* __restrict__ outb,
    int M, int N, int K) {
  __shared__ __align__(16) ushort As[64 * 40];  // +8 bf16 pad per row
  __shared__ __align__(16) ushort Ws[64 * 40];
  int t = threadIdx.x;
  int l = t & 63, w = t >> 6;
  int n0 = blockIdx.x * 64, m0 = blockIdx.y * 64;
  int srow = t >> 2, sc = (t & 3) * 8;
  int lrow = l & 15, lk = (l >> 4) * 8;

  f32x4 acc[4];
#pragma unroll
  for (int nt = 0; nt < 4; nt++) acc[nt] = {0.f, 0.f, 0.f, 0.f};

  for (int kk = 0; kk < K; kk += 32) {
    __syncthreads();
    *(uint4*)&As[srow * 40 + sc] = *(const uint4*)&A[(size_t)(m0 + srow) * K + kk + sc];
    *(uint4*)&Ws[srow * 40 + sc] = *(const uint4*)&W[(size_t)(n0 + srow) * K + kk + sc];
    __syncthreads();
    bf16x8 af = *(const bf16x8*)&As[(16 * w + lrow) * 40 + lk];
#pragma unroll
    for (int nt = 0; nt < 4; nt++) {
      bf16x8 bf = *(const bf16x8*)&Ws[(nt * 16 + lrow) * 40 + lk];
      acc[nt] = __builtin_amdgcn_mfma_f32_16x16x32_bf16(af, bf, acc[nt], 0, 0, 0);
    }
  }

  // C/D layout: col = lane&15, row = (lane>>4)*4 + reg   [verified m89/m91]
#pragma unroll
  for (int nt = 0; nt < 4; nt++) {
    int n = n0 + nt * 16 + lrow;
    float bv = bias[n];
#pragma unroll
    for (int r = 0; r < 4; r++) {
      int m = m0 + 16 * w + (l >> 4) * 4 + r;
      float v = acc[nt][r] + bv;
      if (RELU)  v = fmaxf(v, 0.f);
      if (RESID) v += resid[(size_t)m * N + n];
      if (OUT_F32)  outf[(size_t)m * N + n] = v;
      if (OUT_BF16) outb[(size_t)m * N + n] = f2b(v);
    }
  }
}

// ---------------------------------------------------------------------------
// Fused attention: per block = (b, 8 rows of n), all 8 heads.
//   P0: q tile -> LDS
//   P1: qk[h][n][m] (pre-scaled by log2e/sqrt(DH)) -> LDS fp16
//   P2: Z[i][h][n] = sum_m exp2(|qk*w|); store 1/(Z+1e-10)
//   P3: per 32-m tile: stage w, compute scores (write global), scores@V accum
// LDS: 51456 (qk) + 1024 (zinv) + 12288 (arena: qs | ws+ss) = 64768 B
// ---------------------------------------------------------------------------
#define QKS 402  // dword stride 201 (odd) -> conflict-free row spread

__global__ __launch_bounds__(256) void attn_kernel(
    const ushort* __restrict__ qb, const ushort* __restrict__ kb,
    const ushort* __restrict__ vb, const float* __restrict__ aw,
    float* __restrict__ scores, ushort* __restrict__ attnb) {
  __shared__ __align__(16) __half qk_s[8 * 8 * QKS];
  __shared__ __align__(16) float zinv[256];
  __shared__ __align__(16) float arena[3072];

  int t = threadIdx.x;
  int b = blockIdx.y, n0 = blockIdx.x * 8;
  ushort* qs = (ushort*)arena;

  // P0: load q tile [8][256] bf16
  {
    int row = t >> 5, ch = (t & 31) * 8;
    *(uint4*)&qs[row * 256 + ch] =
        *(const uint4*)&qb[((size_t)b * N_ + n0 + row) * D_ + ch];
  }
  __syncthreads();

  // P1: qk
  {
    int n = t >> 5, ml = t & 31;
    for (int h = 0; h < 8; h++) {
      float qf[32];
      const uint4* qv4 = (const uint4*)&qs[n * 256 + h * 32];
#pragma unroll
      for (int q4 = 0; q4 < 4; q4++) {
        uint4 u = qv4[q4];
        unpack2(u.x, &qf[q4 * 8 + 0]); unpack2(u.y, &qf[q4 * 8 + 2]);
        unpack2(u.z, &qf[q4 * 8 + 4]); unpack2(u.w, &qf[q4 * 8 + 6]);
      }
      for (int m = ml; m < N_; m += 32) {
        const uint4* kv4 = (const uint4*)&kb[((size_t)b * N_ + m) * D_ + h * 32];
        float dot = 0.f;
#pragma unroll
        for (int q4 = 0; q4 < 4; q4++) {
          uint4 u = kv4[q4];
          float kf[8];
          unpack2(u.x, &kf[0]); unpack2(u.y, &kf[2]);
          unpack2(u.z, &kf[4]); unpack2(u.w, &kf[6]);
#pragma unroll
          for (int j = 0; j < 8; j++) dot += qf[q4 * 8 + j] * kf[j];
        }
        qk_s[(h * 8 + n) * QKS + m] = __float2half(dot * QK_SCL);
      }
    }
  }
  __syncthreads();

  // P2: Z
  {
    int i = t >> 6, h = (t >> 3) & 7, n = t & 7;
    const __half* qrow = &qk_s[(h * 8 + n) * QKS];
    const float* wrow = &aw[(((size_t)b * NW_ + i) * N_ + n0 + n) * N_];
    float z = 0.f;
    for (int m = 0; m < N_; m += 4) {
      float4 wv = *(const float4*)&wrow[m];
      float2 f0 = __half22float2(*(const __half2*)&qrow[m]);
      float2 f1 = __half22float2(*(const __half2*)&qrow[m + 2]);
      z += EXP2(fabsf(f0.x * wv.x)) + EXP2(fabsf(f0.y * wv.y)) +
           EXP2(fabsf(f1.x * wv.z)) + EXP2(fabsf(f1.y * wv.w));
    }
    zinv[t] = 1.f / (z + 1e-10f);  // t == i*64 + h*8 + n
  }
  __syncthreads();

  // P3: scores + scores@V
  float* wsm = arena;         // [4][8][32] fp32
  float* ssm = arena + 1024;  // [8][8][32] fp32
  float acc[8] = {0.f, 0.f, 0.f, 0.f, 0.f, 0.f, 0.f, 0.f};
  int h3 = t >> 5, g = t & 31;

  for (int mt = 0; mt < N_; mt += 32) {
    {  // stage w tile
      int i = t >> 6, n = (t >> 3) & 7, q4 = (t & 7) * 4;
      int m = mt + q4;
      if (m < N_)
        *(float4*)&wsm[(i * 8 + n) * 32 + q4] =
            *(const float4*)&aw[(((size_t)b * NW_ + i) * N_ + n0 + n) * N_ + m];
    }
    __syncthreads();
    {  // scores
      int m = mt + g;
      if (m < N_) {
#pragma unroll
        for (int n = 0; n < 8; n++) {
          float qv = __half2float(qk_s[(h3 * 8 + n) * QKS + m]);
          float sc = 0.f;
#pragma unroll
          for (int i = 0; i < 4; i++) {
            float tt = qv * wsm[(i * 8 + n) * 32 + g];
            float e = EXP2(fabsf(tt));
            sc += copysignf(e * zinv[i * 64 + h3 * 8 + n], tt);
          }
          sc *= 0.25f;
          scores[(((size_t)b * H_ + h3) * N_ + n0 + n) * N_ + m] = sc;
          ssm[(h3 * 8 + n) * 32 + g] = sc;
        }
      }
    }
    __syncthreads();
    {  // accumulate attn_out
      int mm_end = min(32, N_ - mt);
      for (int ml = 0; ml < mm_end; ml++) {
        float vv = b2f(vb[((size_t)b * N_ + mt + ml) * D_ + h3 * 32 + g]);
#pragma unroll
        for (int n = 0; n < 8; n++) acc[n] += ssm[(h3 * 8 + n) * 32 + ml] * vv;
      }
    }
    __syncthreads();
  }

#pragma unroll
  for (int n = 0; n < 8; n++)
    attnb[((size_t)b * N_ + n0 + n) * D_ + h3 * 32 + g] = f2b(acc[n]);
}

// ---------------------------------------------------------------------------
// LayerNorm over last dim (256). One block per row. src already holds
// (residual + sublayer output).
// ---------------------------------------------------------------------------
__global__ __launch_bounds__(256) void ln_kernel(
    const float* __restrict__ src, const float* __restrict__ g,
    const float* __restrict__ be, float* __restrict__ outf,
    ushort* __restrict__ outb) {
  int row = blockIdx.x, t = threadIdx.x;
  float v = src[(size_t)row * 256 + t];
  __shared__ float red[4];
  float s = v;
#pragma unroll
  for (int o = 32; o > 0; o >>= 1) s += __shfl_down(s, o, 64);
  if ((t & 63) == 0) red[t >> 6] = s;
  __syncthreads();
  float mean = (red[0] + red[1] + red[2] + red[3]) * (1.f / 256.f);
  __syncthreads();
  float d = v - mean;
  s = d * d;
#pragma unroll
  for (int o = 32; o > 0; o >>= 1) s += __shfl_down(s, o, 64);
  if ((t & 63) == 0) red[t >> 6] = s;
  __syncthreads();
  float var = (red[0] + red[1] + red[2] + red[3]) * (1.f / 256.f);
  float y = d * rsqrtf(var + 1e-5f) * g[t] + be[t];
  outf[(size_t)row * 256 + t] = y;
  if (outb) outb[(size_t)row * 256 + t] = f2b(y);
}

// ---------------------------------------------------------------------------
extern "C" void kernel_launch(void* const* d_in, const int* in_sizes, int n_in,
                              void* d_out, int out_size, void* d_ws,
                              size_t ws_size, hipStream_t stream) {
  const float* x   = (const float*)d_in[0];
  const float* aw  = (const float*)d_in[1];
  const float* Wq  = (const float*)d_in[2];
  const float* bq  = (const float*)d_in[3];
  const float* Wk  = (const float*)d_in[4];
  const float* bk  = (const float*)d_in[5];
  const float* Wv  = (const float*)d_in[6];
  const float* bv  = (const float*)d_in[7];
  const float* Wo  = (const float*)d_in[8];
  const float* bo  = (const float*)d_in[9];
  const float* g1  = (const float*)d_in[10];
  const float* be1 = (const float*)d_in[11];
  const float* W1  = (const float*)d_in[12];
  const float* b1  = (const float*)d_in[13];
  const float* W2  = (const float*)d_in[14];
  const float* b2  = (const float*)d_in[15];
  const float* g2  = (const float*)d_in[16];
  const float* be2 = (const float*)d_in[17];

  if (ws_size < 34340864) return;  // scratch layout requirement

  char* ws = (char*)d_ws;
  ushort* xb    = (ushort*)(ws + 0);          // 3,276,800
  ushort* wqb   = (ushort*)(ws + 3276800);    //   131,072
  ushort* wkb   = (ushort*)(ws + 3407872);
  ushort* wvb   = (ushort*)(ws + 3538944);
  ushort* wob   = (ushort*)(ws + 3670016);
  ushort* w1b   = (ushort*)(ws + 3801088);    //   524,288
  ushort* w2b   = (ushort*)(ws + 4325376);    //   524,288
  ushort* qbuf  = (ushort*)(ws + 4849664);    // 3,276,800
  ushort* kbuf  = (ushort*)(ws + 8126464);
  ushort* vbuf  = (ushort*)(ws + 11403264);
  ushort* attnb = (ushort*)(ws + 14680064);
  float*  ao    = (float*)(ws + 17956864);    // 6,553,600 (reused as ffn2)
  float*  hbuf  = (float*)(ws + 24510464);    // 6,553,600
  ushort* hb    = (ushort*)(ws + 31064064);   // 3,276,800  -> total 34,340,864
  ushort* ffn1b = qbuf;   // reuse q/k/v/attnb region (13,107,200 B), dead by then
  float*  ffn2  = ao;     // reuse ao, dead after LN1

  float* yout   = (float*)d_out;
  float* scores = yout + 1638400;

  convert_kernel<<<2368, 256, 0, stream>>>(x, Wq, Wk, Wv, Wo, W1, W2,
                                           xb, wqb, wkb, wvb, wob, w1b, w2b);
  gemm_bt<0, 0, 0, 1><<<dim3(4, 100), 256, 0, stream>>>(
      xb, wqb, bq, nullptr, nullptr, qbuf, 6400, 256, 256);
  gemm_bt<0, 0, 0, 1><<<dim3(4, 100), 256, 0, stream>>>(
      xb, wkb, bk, nullptr, nullptr, kbuf, 6400, 256, 256);
  gemm_bt<0, 0, 0, 1><<<dim3(4, 100), 256, 0, stream>>>(
      xb, wvb, bv, nullptr, nullptr, vbuf, 6400, 256, 256);
  attn_kernel<<<dim3(50, 16), 256, 0, stream>>>(qbuf, kbuf, vbuf, aw,
                                                scores, attnb);
  gemm_bt<0, 1, 1, 0><<<dim3(4, 100), 256, 0, stream>>>(
      attnb, wob, bo, x, ao, nullptr, 6400, 256, 256);
  ln_kernel<<<6400, 256, 0, stream>>>(ao, g1, be1, hbuf, hb);
  gemm_bt<1, 0, 0, 1><<<dim3(16, 100), 256, 0, stream>>>(
      hb, w1b, b1, nullptr, nullptr, ffn1b, 6400, 1024, 256);
  gemm_bt<0, 1, 1, 0><<<dim3(4, 100), 256, 0, stream>>>(
      ffn1b, w2b, b2, hbuf, ffn2, nullptr, 6400, 256, 1024);
  ln_kernel<<<6400, 256, 0, stream>>>(ffn2, g2, be2, yout, nullptr);
}

// Round 2
// 438.222 us; speedup vs baseline: 1.1545x; 1.1545x over previous
//
#include <hip/hip_runtime.h>
#include <hip/hip_fp16.h>

typedef unsigned int uint32;

#define B_ 16
#define N_ 400
#define D_ 256
#define H_ 8
#define DH_ 32
#define NW_ 4

#if __has_builtin(__builtin_amdgcn_exp2f)
#define EXP2(x) __builtin_amdgcn_exp2f(x)
#else
#define EXP2(x) exp2f(x)
#endif

// log2(e)/sqrt(32): exp(|qk/sqrt(32) * w|) == exp2(|qk*SCL * w|)
#define QK_SCL 0.2550348f

using bf16x8 = __attribute__((ext_vector_type(8))) short;
using f32x4  = __attribute__((ext_vector_type(4))) float;
using f16x2  = __attribute__((ext_vector_type(2))) _Float16;

__device__ __forceinline__ ushort f2b(float f) {
  uint32 u = __float_as_uint(f);
  uint32 r = (u + 0x7fffu + ((u >> 16) & 1u)) >> 16;
  return (ushort)r;
}

// 16-term fp16 dot: c += sum(a[j]*b[j]) over 8 half2 pairs packed in uint4s
__device__ __forceinline__ float dot16(uint4 a, uint4 b, float c) {
#if __has_builtin(__builtin_amdgcn_fdot2)
  const f16x2* pa = (const f16x2*)&a;
  const f16x2* pb = (const f16x2*)&b;
#pragma unroll
  for (int j = 0; j < 4; j++) c = __builtin_amdgcn_fdot2(pa[j], pb[j], c, false);
#else
  const __half2* pa = (const __half2*)&a;
  const __half2* pb = (const __half2*)&b;
#pragma unroll
  for (int j = 0; j < 4; j++) {
    float2 fa = __half22float2(pa[j]);
    float2 fb = __half22float2(pb[j]);
    c = fmaf(fa.x, fb.x, c);
    c = fmaf(fa.y, fb.y, c);
  }
#endif
  return c;
}

// ---------------------------------------------------------------------------
// Convert fp32 inputs -> bf16 scratch copies (x + 6 weight matrices)
// ---------------------------------------------------------------------------
__global__ __launch_bounds__(256) void convert_kernel(
    const float* __restrict__ x,  const float* __restrict__ wq,
    const float* __restrict__ wk, const float* __restrict__ wv,
    const float* __restrict__ wo, const float* __restrict__ w1,
    const float* __restrict__ w2,
    ushort* __restrict__ xb,  ushort* __restrict__ wqb,
    ushort* __restrict__ wkb, ushort* __restrict__ wvb,
    ushort* __restrict__ wob, ushort* __restrict__ w1b,
    ushort* __restrict__ w2b) {
  int gid = blockIdx.x * 256 + threadIdx.x;   // unit = 4 floats
  const float* src; ushort* dst;
  if      (gid < 409600) { src = x;  dst = xb;  }
  else if ((gid -= 409600) < 16384) { src = wq; dst = wqb; }
  else if ((gid -= 16384) < 16384)  { src = wk; dst = wkb; }
  else if ((gid -= 16384) < 16384)  { src = wv; dst = wvb; }
  else if ((gid -= 16384) < 16384)  { src = wo; dst = wob; }
  else if ((gid -= 16384) < 65536)  { src = w1; dst = w1b; }
  else { gid -= 65536; src = w2; dst = w2b; }
  float4 f = ((const float4*)src)[gid];
  ushort4 u;
  u.x = f2b(f.x); u.y = f2b(f.y); u.z = f2b(f.z); u.w = f2b(f.w);
  *(ushort4*)&dst[(size_t)gid * 4] = u;
}

// ---------------------------------------------------------------------------
// Generic bf16 MFMA GEMM: C[M,N] = A[M,K] @ W[N,K]^T + bias, fused epilogue.
// 64x64 tile, 256 threads (4 waves), double-buffered LDS: 1 barrier / K-step.
// ---------------------------------------------------------------------------
template <int RELU, int RESID, int OUT_F32, int OUT_BF16>
__global__ __launch_bounds__(256) void gemm_bt(
    const ushort* __restrict__ A, const ushort* __restrict__ W,
    const float* __restrict__ bias, const float* __restrict__ resid,
    float* __restrict__ outf, ushort* __restrict__ outb,
    int M, int N, int K) {
  __shared__ __align__(16) ushort As[2][64 * 40];  // +8 bf16 pad per row
  __shared__ __align__(16) ushort Ws[2][64 * 40];
  int t = threadIdx.x;
  int l = t & 63, w = t >> 6;
  int n0 = blockIdx.x * 64, m0 = blockIdx.y * 64;
  int srow = t >> 2, sc = (t & 3) * 8;
  int lrow = l & 15, lk = (l >> 4) * 8;

  const uint4* ag = (const uint4*)&A[(size_t)(m0 + srow) * K + sc];
  const uint4* wg = (const uint4*)&W[(size_t)(n0 + srow) * K + sc];
  uint4 ar = ag[0], wr = wg[0];
  int nk = K >> 5;

  f32x4 acc[4];
#pragma unroll
  for (int nt = 0; nt < 4; nt++) acc[nt] = {0.f, 0.f, 0.f, 0.f};

  for (int kk = 0; kk < nk; kk++) {
    int cur = kk & 1;
    *(uint4*)&As[cur][srow * 40 + sc] = ar;
    *(uint4*)&Ws[cur][srow * 40 + sc] = wr;
    if (kk + 1 < nk) { ar = ag[(size_t)(kk + 1) * 4]; wr = wg[(size_t)(kk + 1) * 4]; }
    __syncthreads();
    bf16x8 af = *(const bf16x8*)&As[cur][(16 * w + lrow) * 40 + lk];
#pragma unroll
    for (int nt = 0; nt < 4; nt++) {
      bf16x8 bf = *(const bf16x8*)&Ws[cur][(nt * 16 + lrow) * 40 + lk];
      acc[nt] = __builtin_amdgcn_mfma_f32_16x16x32_bf16(af, bf, acc[nt], 0, 0, 0);
    }
  }

  // C/D layout: col = lane&15, row = (lane>>4)*4 + reg   [verified m89/m91]
#pragma unroll
  for (int nt = 0; nt < 4; nt++) {
    int n = n0 + nt * 16 + lrow;
    float bv = bias[n];
#pragma unroll
    for (int r = 0; r < 4; r++) {
      int m = m0 + 16 * w + (l >> 4) * 4 + r;
      float v = acc[nt][r] + bv;
      if (RELU)  v = fmaxf(v, 0.f);
      if (RESID) v += resid[(size_t)m * N + n];
      if (OUT_F32)  outf[(size_t)m * N + n] = v;
      if (OUT_BF16) outb[(size_t)m * N + n] = f2b(v);
    }
  }
}

// ---------------------------------------------------------------------------
// Fused QKV GEMM: one launch, z picks {q,k,v}. Same 64x64 MFMA core.
// q,k -> fp16 [B*N, D]; v -> fp16 TRANSPOSED vt[b][d][m] (stride N_=400).
// ---------------------------------------------------------------------------
__global__ __launch_bounds__(256) void qkv_gemm(
    const ushort* __restrict__ xb, const ushort* __restrict__ wq,
    const ushort* __restrict__ wk, const ushort* __restrict__ wv,
    const float* __restrict__ bq, const float* __restrict__ bk,
    const float* __restrict__ bv,
    __half* __restrict__ qh, __half* __restrict__ kh, __half* __restrict__ vt) {
  __shared__ __align__(16) ushort As[2][64 * 40];
  __shared__ __align__(16) ushort Ws[2][64 * 40];
  int z = blockIdx.z;
  const ushort* W = (z == 0) ? wq : (z == 1) ? wk : wv;
  const float* bias = (z == 0) ? bq : (z == 1) ? bk : bv;

  int t = threadIdx.x;
  int l = t & 63, w = t >> 6;
  int n0 = blockIdx.x * 64, m0 = blockIdx.y * 64;
  int srow = t >> 2, sc = (t & 3) * 8;
  int lrow = l & 15, lk = (l >> 4) * 8;

  const uint4* ag = (const uint4*)&xb[(size_t)(m0 + srow) * 256 + sc];
  const uint4* wg = (const uint4*)&W[(size_t)(n0 + srow) * 256 + sc];
  uint4 ar = ag[0], wr = wg[0];

  f32x4 acc[4];
#pragma unroll
  for (int nt = 0; nt < 4; nt++) acc[nt] = {0.f, 0.f, 0.f, 0.f};

  for (int kk = 0; kk < 8; kk++) {
    int cur = kk & 1;
    *(uint4*)&As[cur][srow * 40 + sc] = ar;
    *(uint4*)&Ws[cur][srow * 40 + sc] = wr;
    if (kk + 1 < 8) { ar = ag[(kk + 1) * 4]; wr = wg[(kk + 1) * 4]; }
    __syncthreads();
    bf16x8 af = *(const bf16x8*)&As[cur][(16 * w + lrow) * 40 + lk];
#pragma unroll
    for (int nt = 0; nt < 4; nt++) {
      bf16x8 bf = *(const bf16x8*)&Ws[cur][(nt * 16 + lrow) * 40 + lk];
      acc[nt] = __builtin_amdgcn_mfma_f32_16x16x32_bf16(af, bf, acc[nt], 0, 0, 0);
    }
  }

  int mb = m0 + 16 * w + (l >> 4) * 4;  // multiple of 4 -> never crosses b*400
#pragma unroll
  for (int nt = 0; nt < 4; nt++) {
    int n = n0 + nt * 16 + lrow;
    float bvv = bias[n];
    if (z < 2) {
      __half* out = z ? kh : qh;
#pragma unroll
      for (int r = 0; r < 4; r++)
        out[(size_t)(mb + r) * 256 + n] = __float2half(acc[nt][r] + bvv);
    } else {
      int b = mb / 400;
      int mi = mb - b * 400;
      __half h4[4];
#pragma unroll
      for (int r = 0; r < 4; r++) h4[r] = __float2half(acc[nt][r] + bvv);
      *(uint2*)&vt[((size_t)b * 256 + n) * 400 + mi] = *(uint2*)h4;
    }
  }
}

// ---------------------------------------------------------------------------
// Fused attention v2: block = (b, n-tile of 8, ONE head). Grid 6400, LDS 13 KB.
// Block-id swizzle: all 8 head-blocks of one (b,n0) share id%8 -> same XCD,
// so aw rows are L2-shared across heads. 3 barriers per block total.
//   P1: qk[8n][400m] via fp16 dot2 -> LDS fp16 (pre-scaled by log2e/sqrt(DH))
//   P2: zinv[i][n] = 1/(sum_m exp2(|qk*w|)+1e-10)   (8 lanes/row + shfl_xor)
//   P3a: scores (4 m per thread, float4 w loads), s -> LDS fp16
//   P3b: attn_out[n][d] via fp16 dot2 against pre-transposed vt
// ---------------------------------------------------------------------------
#define QKP 408  // halves; row pitch 816 B (16B-aligned, non-pow2 bank spread)

__global__ __launch_bounds__(256, 6) void attn_kernel(
    const __half* __restrict__ qh, const __half* __restrict__ kh,
    const __half* __restrict__ vt, const float* __restrict__ aw,
    float* __restrict__ scores, ushort* __restrict__ attnb) {
  __shared__ __align__(16) __half qk_s[8 * QKP];
  __shared__ __align__(16) __half ssm[8 * QKP];
  __shared__ float zinv[32];

  int id = blockIdx.x;
  int combo = ((id >> 6) << 3) | (id & 7);  // 0..799, same for all 8 heads
  int hh = (id >> 3) & 7;
  int b = combo / 50;
  int n0 = (combo - b * 50) * 8;
  int t = threadIdx.x;

  // ---- P1: qk ----
  {
    int n = t >> 5, ml = t & 31;
    const uint4* qp = (const uint4*)&qh[((size_t)b * N_ + n0 + n) * D_ + hh * 32];
    uint4 q0 = qp[0], q1 = qp[1], q2 = qp[2], q3 = qp[3];
    for (int m = ml; m < N_; m += 32) {
      const uint4* kp = (const uint4*)&kh[((size_t)b * N_ + m) * D_ + hh * 32];
      uint4 k0 = kp[0], k1 = kp[1], k2 = kp[2], k3 = kp[3];
      float dot = 0.f;
      dot = dot16(q0, k0, dot);
      dot = dot16(q1, k1, dot);
      dot = dot16(q2, k2, dot);
      dot = dot16(q3, k3, dot);
      qk_s[n * QKP + m] = __float2half(dot * QK_SCL);
    }
  }
  __syncthreads();

  // ---- P2: Z ----
  {
    int r = t >> 3, p = t & 7;          // r = i*8+n
    int i = r >> 3, n = r & 7;
    const __half* qrow = &qk_s[n * QKP];
    const float* wrow = &aw[(((size_t)b * NW_ + i) * N_ + n0 + n) * N_];
    float z = 0.f;
    for (int m = p * 4; m < N_; m += 32) {
      float4 wv = *(const float4*)&wrow[m];
      float2 f0 = __half22float2(*(const __half2*)&qrow[m]);
      float2 f1 = __half22float2(*(const __half2*)&qrow[m + 2]);
      z += EXP2(fabsf(f0.x * wv.x)) + EXP2(fabsf(f0.y * wv.y)) +
           EXP2(fabsf(f1.x * wv.z)) + EXP2(fabsf(f1.y * wv.w));
    }
    z += __shfl_xor(z, 1);
    z += __shfl_xor(z, 2);
    z += __shfl_xor(z, 4);
    if (p == 0) zinv[r] = 1.f / (z + 1e-10f);
  }
  __syncthreads();

  // ---- P3a: scores ----
  {
    int n = t >> 5, p = t & 31;
    float zr[4] = {zinv[n], zinv[8 + n], zinv[16 + n], zinv[24 + n]};
    const __half* qrow = &qk_s[n * QKP];
    __half* srow = &ssm[n * QKP];
    const float* awn = &aw[((size_t)b * NW_ * N_ + (n0 + n)) * N_];  // +i*160000
    float* scout = &scores[(((size_t)b * H_ + hh) * N_ + n0 + n) * N_];
    for (int mb = p * 4; mb < N_; mb += 128) {
      float2 f0 = __half22float2(*(const __half2*)&qrow[mb]);
      float2 f1 = __half22float2(*(const __half2*)&qrow[mb + 2]);
      float qf[4] = {f0.x, f0.y, f1.x, f1.y};
      float sc[4] = {0.f, 0.f, 0.f, 0.f};
#pragma unroll
      for (int i = 0; i < 4; i++) {
        float4 wv = *(const float4*)&awn[(size_t)i * N_ * N_ + mb];
        float t0 = qf[0] * wv.x; sc[0] += copysignf(EXP2(fabsf(t0)) * zr[i], t0);
        float t1 = qf[1] * wv.y; sc[1] += copysignf(EXP2(fabsf(t1)) * zr[i], t1);
        float t2 = qf[2] * wv.z; sc[2] += copysignf(EXP2(fabsf(t2)) * zr[i], t2);
        float t3 = qf[3] * wv.w; sc[3] += copysignf(EXP2(fabsf(t3)) * zr[i], t3);
      }
      float4 o = {sc[0] * 0.25f, sc[1] * 0.25f, sc[2] * 0.25f, sc[3] * 0.25f};
      *(float4*)&scout[mb] = o;
      __half h4[4] = {__float2half(o.x), __float2half(o.y),
                      __float2half(o.z), __float2half(o.w)};
      *(uint2*)&srow[mb] = *(uint2*)h4;
    }
  }
  __syncthreads();

  // ---- P3b: PV ----
  {
    int n = t >> 5, d = t & 31;
    const uint4* vr = (const uint4*)&vt[((size_t)b * D_ + hh * 32 + d) * N_];
    const uint4* sr = (const uint4*)&ssm[n * QKP];
    float acc = 0.f;
    for (int g = 0; g < 50; g++) {
      uint4 sv = sr[g];
      uint4 vv = vr[g];
      acc = dot16(sv, vv, acc);
    }
    attnb[((size_t)b * N_ + n0 + n) * D_ + hh * 32 + d] = f2b(acc);
  }
}

// ---------------------------------------------------------------------------
// LayerNorm over last dim (256). One block per row.
// ---------------------------------------------------------------------------
__global__ __launch_bounds__(256) void ln_kernel(
    const float* __restrict__ src, const float* __restrict__ g,
    const float* __restrict__ be, float* __restrict__ outf,
    ushort* __restrict__ outb) {
  int row = blockIdx.x, t = threadIdx.x;
  float v = src[(size_t)row * 256 + t];
  __shared__ float red[4];
  float s = v;
#pragma unroll
  for (int o = 32; o > 0; o >>= 1) s += __shfl_down(s, o, 64);
  if ((t & 63) == 0) red[t >> 6] = s;
  __syncthreads();
  float mean = (red[0] + red[1] + red[2] + red[3]) * (1.f / 256.f);
  __syncthreads();
  float d = v - mean;
  s = d * d;
#pragma unroll
  for (int o = 32; o > 0; o >>= 1) s += __shfl_down(s, o, 64);
  if ((t & 63) == 0) red[t >> 6] = s;
  __syncthreads();
  float var = (red[0] + red[1] + red[2] + red[3]) * (1.f / 256.f);
  float y = d * rsqrtf(var + 1e-5f) * g[t] + be[t];
  outf[(size_t)row * 256 + t] = y;
  if (outb) outb[(size_t)row * 256 + t] = f2b(y);
}

// ---------------------------------------------------------------------------
extern "C" void kernel_launch(void* const* d_in, const int* in_sizes, int n_in,
                              void* d_out, int out_size, void* d_ws,
                              size_t ws_size, hipStream_t stream) {
  const float* x   = (const float*)d_in[0];
  const float* aw  = (const float*)d_in[1];
  const float* Wq  = (const float*)d_in[2];
  const float* bq  = (const float*)d_in[3];
  const float* Wk  = (const float*)d_in[4];
  const float* bk  = (const float*)d_in[5];
  const float* Wv  = (const float*)d_in[6];
  const float* bv  = (const float*)d_in[7];
  const float* Wo  = (const float*)d_in[8];
  const float* bo  = (const float*)d_in[9];
  const float* g1  = (const float*)d_in[10];
  const float* be1 = (const float*)d_in[11];
  const float* W1  = (const float*)d_in[12];
  const float* b1  = (const float*)d_in[13];
  const float* W2  = (const float*)d_in[14];
  const float* b2  = (const float*)d_in[15];
  const float* g2  = (const float*)d_in[16];
  const float* be2 = (const float*)d_in[17];

  if (ws_size < 34340864) return;  // scratch layout requirement

  char* ws = (char*)d_ws;
  ushort* xb    = (ushort*)(ws + 0);          // 3,276,800
  ushort* wqb   = (ushort*)(ws + 3276800);    //   131,072
  ushort* wkb   = (ushort*)(ws + 3407872);
  ushort* wvb   = (ushort*)(ws + 3538944);
  ushort* wob   = (ushort*)(ws + 3670016);
  ushort* w1b   = (ushort*)(ws + 3801088);    //   524,288
  ushort* w2b   = (ushort*)(ws + 4325376);    //   524,288
  __half* qhb   = (__half*)(ws + 4849664);    // 3,276,800
  __half* khb   = (__half*)(ws + 8126464);
  __half* vtb   = (__half*)(ws + 11403264);   // transposed [b][d][m]
  ushort* attnb = (ushort*)(ws + 14680064);
  float*  ao    = (float*)(ws + 17956864);    // 6,553,600 (reused as ffn2)
  float*  hbuf  = (float*)(ws + 24510464);    // 6,553,600
  ushort* hb    = (ushort*)(ws + 31064064);   // 3,276,800  -> total 34,340,864
  ushort* ffn1b = (ushort*)qhb;  // reuse q/k/v/attnb region, dead by then
  float*  ffn2  = ao;            // reuse ao, dead after LN1

  float* yout   = (float*)d_out;
  float* scores = yout + 1638400;

  convert_kernel<<<2368, 256, 0, stream>>>(x, Wq, Wk, Wv, Wo, W1, W2,
                                           xb, wqb, wkb, wvb, wob, w1b, w2b);
  qkv_gemm<<<dim3(4, 100, 3), 256, 0, stream>>>(
      xb, wqb, wkb, wvb, bq, bk, bv, qhb, khb, vtb);
  attn_kernel<<<6400, 256, 0, stream>>>(qhb, khb, vtb, aw, scores, attnb);
  gemm_bt<0, 1, 1, 0><<<dim3(4, 100), 256, 0, stream>>>(
      attnb, wob, bo, x, ao, nullptr, 6400, 256, 256);
  ln_kernel<<<6400, 256, 0, stream>>>(ao, g1, be1, hbuf, hb);
  gemm_bt<1, 0, 0, 1><<<dim3(16, 100), 256, 0, stream>>>(
      hb, w1b, b1, nullptr, nullptr, ffn1b, 6400, 1024, 256);
  gemm_bt<0, 1, 1, 0><<<dim3(4, 100), 256, 0, stream>>>(
      ffn1b, w2b, b2, hbuf, ffn2, nullptr, 6400, 256, 1024);
  ln_kernel<<<6400, 256, 0, stream>>>(ffn2, g2, be2, yout, nullptr);
}

// Round 3
// 272.056 us; speedup vs baseline: 1.8596x; 1.6108x over previous
//
#include <hip/hip_runtime.h>
#include <hip/hip_fp16.h>

typedef unsigned int uint32;

#define B_ 16
#define N_ 400
#define D_ 256
#define H_ 8
#define DH_ 32
#define NW_ 4

#if __has_builtin(__builtin_amdgcn_exp2f)
#define EXP2(x) __builtin_amdgcn_exp2f(x)
#else
#define EXP2(x) exp2f(x)
#endif

// log2(e)/sqrt(32): exp(|qk/sqrt(32) * w|) == exp2(|qk*SCL * w|)
#define QK_SCL 0.2550348f

using bf16x8 = __attribute__((ext_vector_type(8))) short;
using f16x8  = __attribute__((ext_vector_type(8))) _Float16;
using f32x4  = __attribute__((ext_vector_type(4))) float;

__device__ __forceinline__ ushort f2b(float f) {
  uint32 u = __float_as_uint(f);
  uint32 r = (u + 0x7fffu + ((u >> 16) & 1u)) >> 16;
  return (ushort)r;
}

// ---------------------------------------------------------------------------
// Convert fp32 inputs -> bf16 scratch copies (x + 6 weight matrices)
// ---------------------------------------------------------------------------
__global__ __launch_bounds__(256) void convert_kernel(
    const float* __restrict__ x,  const float* __restrict__ wq,
    const float* __restrict__ wk, const float* __restrict__ wv,
    const float* __restrict__ wo, const float* __restrict__ w1,
    const float* __restrict__ w2,
    ushort* __restrict__ xb,  ushort* __restrict__ wqb,
    ushort* __restrict__ wkb, ushort* __restrict__ wvb,
    ushort* __restrict__ wob, ushort* __restrict__ w1b,
    ushort* __restrict__ w2b) {
  int gid = blockIdx.x * 256 + threadIdx.x;   // unit = 4 floats
  const float* src; ushort* dst;
  if      (gid < 409600) { src = x;  dst = xb;  }
  else if ((gid -= 409600) < 16384) { src = wq; dst = wqb; }
  else if ((gid -= 16384) < 16384)  { src = wk; dst = wkb; }
  else if ((gid -= 16384) < 16384)  { src = wv; dst = wvb; }
  else if ((gid -= 16384) < 16384)  { src = wo; dst = wob; }
  else if ((gid -= 16384) < 65536)  { src = w1; dst = w1b; }
  else { gid -= 65536; src = w2; dst = w2b; }
  float4 f = ((const float4*)src)[gid];
  ushort4 u;
  u.x = f2b(f.x); u.y = f2b(f.y); u.z = f2b(f.z); u.w = f2b(f.w);
  *(ushort4*)&dst[(size_t)gid * 4] = u;
}

// ---------------------------------------------------------------------------
// Generic bf16 MFMA GEMM: C[M,N] = A[M,K] @ W[N,K]^T + bias, fused epilogue.
// 64x64 tile, 256 threads (4 waves), double-buffered LDS: 1 barrier / K-step.
// ---------------------------------------------------------------------------
template <int RELU, int RESID, int OUT_F32, int OUT_BF16>
__global__ __launch_bounds__(256) void gemm_bt(
    const ushort* __restrict__ A, const ushort* __restrict__ W,
    const float* __restrict__ bias, const float* __restrict__ resid,
    float* __restrict__ outf, ushort* __restrict__ outb,
    int M, int N, int K) {
  __shared__ __align__(16) ushort As[2][64 * 40];  // +8 bf16 pad per row
  __shared__ __align__(16) ushort Ws[2][64 * 40];
  int t = threadIdx.x;
  int l = t & 63, w = t >> 6;
  int n0 = blockIdx.x * 64, m0 = blockIdx.y * 64;
  int srow = t >> 2, sc = (t & 3) * 8;
  int lrow = l & 15, lk = (l >> 4) * 8;

  const uint4* ag = (const uint4*)&A[(size_t)(m0 + srow) * K + sc];
  const uint4* wg = (const uint4*)&W[(size_t)(n0 + srow) * K + sc];
  uint4 ar = ag[0], wr = wg[0];
  int nk = K >> 5;

  f32x4 acc[4];
#pragma unroll
  for (int nt = 0; nt < 4; nt++) acc[nt] = {0.f, 0.f, 0.f, 0.f};

  for (int kk = 0; kk < nk; kk++) {
    int cur = kk & 1;
    *(uint4*)&As[cur][srow * 40 + sc] = ar;
    *(uint4*)&Ws[cur][srow * 40 + sc] = wr;
    if (kk + 1 < nk) { ar = ag[(size_t)(kk + 1) * 4]; wr = wg[(size_t)(kk + 1) * 4]; }
    __syncthreads();
    bf16x8 af = *(const bf16x8*)&As[cur][(16 * w + lrow) * 40 + lk];
#pragma unroll
    for (int nt = 0; nt < 4; nt++) {
      bf16x8 bf = *(const bf16x8*)&Ws[cur][(nt * 16 + lrow) * 40 + lk];
      acc[nt] = __builtin_amdgcn_mfma_f32_16x16x32_bf16(af, bf, acc[nt], 0, 0, 0);
    }
  }

  // C/D layout: col = lane&15, row = (lane>>4)*4 + reg   [verified m89/m91]
#pragma unroll
  for (int nt = 0; nt < 4; nt++) {
    int n = n0 + nt * 16 + lrow;
    float bv = bias[n];
#pragma unroll
    for (int r = 0; r < 4; r++) {
      int m = m0 + 16 * w + (l >> 4) * 4 + r;
      float v = acc[nt][r] + bv;
      if (RELU)  v = fmaxf(v, 0.f);
      if (RESID) v += resid[(size_t)m * N + n];
      if (OUT_F32)  outf[(size_t)m * N + n] = v;
      if (OUT_BF16) outb[(size_t)m * N + n] = f2b(v);
    }
  }
}

// ---------------------------------------------------------------------------
// Fused QKV GEMM: one launch, z picks {q,k,v}. Same 64x64 MFMA core.
// q -> fp16 HEAD-MAJOR [b][h][m][32], pre-scaled by QK_SCL.
// k -> fp16 HEAD-MAJOR [b][h][m][32].
// v -> fp16 TRANSPOSED vt[b][d][m] (stride N_=400); d = h*32+dh.
// ---------------------------------------------------------------------------
__global__ __launch_bounds__(256) void qkv_gemm(
    const ushort* __restrict__ xb, const ushort* __restrict__ wq,
    const ushort* __restrict__ wk, const ushort* __restrict__ wv,
    const float* __restrict__ bq, const float* __restrict__ bk,
    const float* __restrict__ bv,
    _Float16* __restrict__ qh, _Float16* __restrict__ kh,
    _Float16* __restrict__ vt) {
  __shared__ __align__(16) ushort As[2][64 * 40];
  __shared__ __align__(16) ushort Ws[2][64 * 40];
  int z = blockIdx.z;
  const ushort* W = (z == 0) ? wq : (z == 1) ? wk : wv;
  const float* bias = (z == 0) ? bq : (z == 1) ? bk : bv;

  int t = threadIdx.x;
  int l = t & 63, w = t >> 6;
  int n0 = blockIdx.x * 64, m0 = blockIdx.y * 64;
  int srow = t >> 2, sc = (t & 3) * 8;
  int lrow = l & 15, lk = (l >> 4) * 8;

  const uint4* ag = (const uint4*)&xb[(size_t)(m0 + srow) * 256 + sc];
  const uint4* wg = (const uint4*)&W[(size_t)(n0 + srow) * 256 + sc];
  uint4 ar = ag[0], wr = wg[0];

  f32x4 acc[4];
#pragma unroll
  for (int nt = 0; nt < 4; nt++) acc[nt] = {0.f, 0.f, 0.f, 0.f};

  for (int kk = 0; kk < 8; kk++) {
    int cur = kk & 1;
    *(uint4*)&As[cur][srow * 40 + sc] = ar;
    *(uint4*)&Ws[cur][srow * 40 + sc] = wr;
    if (kk + 1 < 8) { ar = ag[(kk + 1) * 4]; wr = wg[(kk + 1) * 4]; }
    __syncthreads();
    bf16x8 af = *(const bf16x8*)&As[cur][(16 * w + lrow) * 40 + lk];
#pragma unroll
    for (int nt = 0; nt < 4; nt++) {
      bf16x8 bf = *(const bf16x8*)&Ws[cur][(nt * 16 + lrow) * 40 + lk];
      acc[nt] = __builtin_amdgcn_mfma_f32_16x16x32_bf16(af, bf, acc[nt], 0, 0, 0);
    }
  }

  int mb = m0 + 16 * w + (l >> 4) * 4;  // multiple of 4 -> never crosses b*400
  int bb = mb / 400;
  int mi = mb - bb * 400;
#pragma unroll
  for (int nt = 0; nt < 4; nt++) {
    int n = n0 + nt * 16 + lrow;
    float bvv = bias[n];
    if (z < 2) {
      _Float16* out = z ? kh : qh;
      float scl = z ? 1.f : QK_SCL;
      int hh = n >> 5, dd = n & 31;
      _Float16* dst = out + (((size_t)(bb * 8 + hh)) * 400 + mi) * 32 + dd;
#pragma unroll
      for (int r = 0; r < 4; r++)
        dst[(size_t)r * 32] = (_Float16)((acc[nt][r] + bvv) * scl);
    } else {
      _Float16 h4[4];
#pragma unroll
      for (int r = 0; r < 4; r++) h4[r] = (_Float16)(acc[nt][r] + bvv);
      *(uint2*)&vt[((size_t)bb * 256 + n) * 400 + mi] = *(uint2*)h4;
    }
  }
}

// ---------------------------------------------------------------------------
// Fused attention v3: block = (b, head, 16 q-rows). Grid 3200, LDS 13.6 KB.
// MFMA for qk and PV; all global fragment loads are fully coalesced
// (lanes tile 16 rows x 64 B = 1 KB contiguous per wave instruction).
// XCD swizzle: 8 head-blocks of one (b,n0) share id%8 -> same XCD -> aw in L2.
//   P1: S[16n][400m] = (Q*scl) @ K^T via 25 mfma_16x16x32_f16 -> LDS fp16
//   P2: zinv[i][n] = 0.25/(sum_m exp2(|S*w|)+1e-10)
//   P3a: scores = sum_i sign*exp2*zinv -> global (float4) + S overwritten fp16
//   P3b: O[16n][32d] = S @ V via mfma against vt rows; cross-wave LDS reduce
// ---------------------------------------------------------------------------
#define SP 416  // S row pitch in halves (832 B, 16B-aligned); 13 chunks of 32

__global__ __launch_bounds__(256) void attn_kernel(
    const _Float16* __restrict__ qh, const _Float16* __restrict__ kh,
    const _Float16* __restrict__ vt, const float* __restrict__ aw,
    float* __restrict__ scores, ushort* __restrict__ attnb) {
  __shared__ __align__(16) char smem[16 * SP * 2 + 256];
  __half* S = (__half*)smem;               // [16][SP] fp16
  float* zin = (float*)(smem + 16 * SP * 2);  // [4i][16n]

  int id = blockIdx.x;
  int c = ((id >> 6) << 3) | (id & 7);  // 0..399: (b, n-tile) combo
  int hh = (id >> 3) & 7;
  int b = c / 25;
  int n0 = (c - b * 25) * 16;

  int t = threadIdx.x;
  int w = t >> 6, l = t & 63;
  int lq = l >> 4, lr = l & 15;

  // ---- P1: S = (Q*scl) @ K^T ----
  {
    const _Float16* qbase = qh + (((size_t)(b * 8 + hh)) * 400 + n0) * 32;
    const _Float16* kbase = kh + ((size_t)(b * 8 + hh)) * 400 * 32;
    f16x8 af = *(const f16x8*)(qbase + lr * 32 + lq * 8);
    for (int mt = w; mt < 25; mt += 4) {
      f16x8 bf = *(const f16x8*)(kbase + (size_t)(mt * 16 + lr) * 32 + lq * 8);
      f32x4 cc = {0.f, 0.f, 0.f, 0.f};
      cc = __builtin_amdgcn_mfma_f32_16x16x32_f16(af, bf, cc, 0, 0, 0);
#pragma unroll
      for (int r = 0; r < 4; r++)
        S[(lq * 4 + r) * SP + mt * 16 + lr] = __float2half(cc[r]);
    }
  }
  __syncthreads();

  // ---- P2: Z (4 threads per (i,n) row) ----
  {
    int r = t >> 2, p = t & 3;
    int i = r >> 4, n = r & 15;
    const float* wrow = aw + (((size_t)(b * 4 + i)) * 400 + n0 + n) * 400;
    const __half* srow = S + n * SP;
    float z = 0.f;
    for (int m = p * 4; m < 400; m += 16) {
      float4 wv = *(const float4*)(wrow + m);
      float2 f0 = __half22float2(*(const __half2*)(srow + m));
      float2 f1 = __half22float2(*(const __half2*)(srow + m + 2));
      z += EXP2(fabsf(f0.x * wv.x)) + EXP2(fabsf(f0.y * wv.y)) +
           EXP2(fabsf(f1.x * wv.z)) + EXP2(fabsf(f1.y * wv.w));
    }
    z += __shfl_xor(z, 1);
    z += __shfl_xor(z, 2);
    if (p == 0) zin[r] = 0.25f / (z + 1e-10f);  // folds the /NW
  }
  __syncthreads();

  // ---- P3a: scores; overwrite S in place with normalized fp16 scores ----
  {
    int n = t >> 4, p = t & 15;
    float zz[4] = {zin[n], zin[16 + n], zin[32 + n], zin[48 + n]};
    __half* srow = S + n * SP;
    const float* awn = aw + (((size_t)(b * 4)) * 400 + n0 + n) * 400;
    float* scout = scores + (((size_t)(b * 8 + hh)) * 400 + n0 + n) * 400;
    for (int m = p * 4; m < 448; m += 64) {
      if (m < 400) {
        float2 f0 = __half22float2(*(const __half2*)(srow + m));
        float2 f1 = __half22float2(*(const __half2*)(srow + m + 2));
        float q0 = f0.x, q1 = f0.y, q2 = f1.x, q3 = f1.y;
        float s0 = 0.f, s1 = 0.f, s2 = 0.f, s3 = 0.f;
#pragma unroll
        for (int i = 0; i < 4; i++) {
          float4 wv = *(const float4*)(awn + (size_t)i * 160000 + m);
          float t0 = q0 * wv.x; s0 += copysignf(EXP2(fabsf(t0)) * zz[i], t0);
          float t1 = q1 * wv.y; s1 += copysignf(EXP2(fabsf(t1)) * zz[i], t1);
          float t2 = q2 * wv.z; s2 += copysignf(EXP2(fabsf(t2)) * zz[i], t2);
          float t3 = q3 * wv.w; s3 += copysignf(EXP2(fabsf(t3)) * zz[i], t3);
        }
        float4 o = {s0, s1, s2, s3};
        *(float4*)(scout + m) = o;
        __half h4[4] = {__float2half(s0), __float2half(s1),
                        __float2half(s2), __float2half(s3)};
        *(uint2*)(srow + m) = *(uint2*)h4;
      } else if (m < 416) {
        uint2 zero = {0u, 0u};
        *(uint2*)(srow + m) = zero;  // zero-pad cols 400..415 for PV chunks
      }
    }
  }
  __syncthreads();

  // ---- P3b: O = S @ V (13 chunks of 32 m, split across waves) ----
  const _Float16* vbase = vt + (((size_t)b) * 256 + hh * 32) * 400;
  f32x4 a0 = {0.f, 0.f, 0.f, 0.f}, a1 = {0.f, 0.f, 0.f, 0.f};
  const _Float16* Sh = (const _Float16*)S;
  for (int c2 = w; c2 < 13; c2 += 4) {
    f16x8 sf = *(const f16x8*)(Sh + lr * SP + c2 * 32 + lq * 8);
    f16x8 v0 = *(const f16x8*)(vbase + (size_t)lr * 400 + c2 * 32 + lq * 8);
    f16x8 v1 = *(const f16x8*)(vbase + (size_t)(16 + lr) * 400 + c2 * 32 + lq * 8);
    a0 = __builtin_amdgcn_mfma_f32_16x16x32_f16(sf, v0, a0, 0, 0, 0);
    a1 = __builtin_amdgcn_mfma_f32_16x16x32_f16(sf, v1, a1, 0, 0, 0);
  }
  __syncthreads();  // all S reads done before overwriting as float scratch
  float* Of = (float*)smem;  // [4w][16n][32d]
#pragma unroll
  for (int r = 0; r < 4; r++) {
    Of[(w * 16 + lq * 4 + r) * 32 + lr] = a0[r];
    Of[(w * 16 + lq * 4 + r) * 32 + 16 + lr] = a1[r];
  }
  __syncthreads();
  for (int o = t; o < 512; o += 256) {
    int n = o >> 5, d = o & 31;
    float s = Of[n * 32 + d] + Of[512 + n * 32 + d] +
              Of[1024 + n * 32 + d] + Of[1536 + n * 32 + d];
    attnb[((size_t)(b * 400 + n0 + n)) * 256 + hh * 32 + d] = f2b(s);
  }
}

// ---------------------------------------------------------------------------
// LayerNorm over last dim (256). One block per row.
// ---------------------------------------------------------------------------
__global__ __launch_bounds__(256) void ln_kernel(
    const float* __restrict__ src, const float* __restrict__ g,
    const float* __restrict__ be, float* __restrict__ outf,
    ushort* __restrict__ outb) {
  int row = blockIdx.x, t = threadIdx.x;
  float v = src[(size_t)row * 256 + t];
  __shared__ float red[4];
  float s = v;
#pragma unroll
  for (int o = 32; o > 0; o >>= 1) s += __shfl_down(s, o, 64);
  if ((t & 63) == 0) red[t >> 6] = s;
  __syncthreads();
  float mean = (red[0] + red[1] + red[2] + red[3]) * (1.f / 256.f);
  __syncthreads();
  float d = v - mean;
  s = d * d;
#pragma unroll
  for (int o = 32; o > 0; o >>= 1) s += __shfl_down(s, o, 64);
  if ((t & 63) == 0) red[t >> 6] = s;
  __syncthreads();
  float var = (red[0] + red[1] + red[2] + red[3]) * (1.f / 256.f);
  float y = d * rsqrtf(var + 1e-5f) * g[t] + be[t];
  outf[(size_t)row * 256 + t] = y;
  if (outb) outb[(size_t)row * 256 + t] = f2b(y);
}

// ---------------------------------------------------------------------------
extern "C" void kernel_launch(void* const* d_in, const int* in_sizes, int n_in,
                              void* d_out, int out_size, void* d_ws,
                              size_t ws_size, hipStream_t stream) {
  const float* x   = (const float*)d_in[0];
  const float* aw  = (const float*)d_in[1];
  const float* Wq  = (const float*)d_in[2];
  const float* bq  = (const float*)d_in[3];
  const float* Wk  = (const float*)d_in[4];
  const float* bk  = (const float*)d_in[5];
  const float* Wv  = (const float*)d_in[6];
  const float* bv  = (const float*)d_in[7];
  const float* Wo  = (const float*)d_in[8];
  const float* bo  = (const float*)d_in[9];
  const float* g1  = (const float*)d_in[10];
  const float* be1 = (const float*)d_in[11];
  const float* W1  = (const float*)d_in[12];
  const float* b1  = (const float*)d_in[13];
  const float* W2  = (const float*)d_in[14];
  const float* b2  = (const float*)d_in[15];
  const float* g2  = (const float*)d_in[16];
  const float* be2 = (const float*)d_in[17];

  if (ws_size < 34340864) return;  // scratch layout requirement

  char* ws = (char*)d_ws;
  ushort*   xb    = (ushort*)(ws + 0);          // 3,276,800
  ushort*   wqb   = (ushort*)(ws + 3276800);    //   131,072
  ushort*   wkb   = (ushort*)(ws + 3407872);
  ushort*   wvb   = (ushort*)(ws + 3538944);
  ushort*   wob   = (ushort*)(ws + 3670016);
  ushort*   w1b   = (ushort*)(ws + 3801088);    //   524,288
  ushort*   w2b   = (ushort*)(ws + 4325376);    //   524,288
  _Float16* qhb   = (_Float16*)(ws + 4849664);  // 3,276,800  [b][h][m][32]*scl
  _Float16* khb   = (_Float16*)(ws + 8126464);  //            [b][h][m][32]
  _Float16* vtb   = (_Float16*)(ws + 11403264); //            [b][d][m]
  ushort*   attnb = (ushort*)(ws + 14680064);
  float*    ao    = (float*)(ws + 17956864);    // 6,553,600 (reused as ffn2)
  float*    hbuf  = (float*)(ws + 24510464);    // 6,553,600
  ushort*   hb    = (ushort*)(ws + 31064064);   // 3,276,800 -> total 34,340,864
  ushort*   ffn1b = (ushort*)qhb;  // reuse q/k/v region, dead by then
  float*    ffn2  = ao;            // reuse ao, dead after LN1

  float* yout   = (float*)d_out;
  float* scores = yout + 1638400;

  convert_kernel<<<2368, 256, 0, stream>>>(x, Wq, Wk, Wv, Wo, W1, W2,
                                           xb, wqb, wkb, wvb, wob, w1b, w2b);
  qkv_gemm<<<dim3(4, 100, 3), 256, 0, stream>>>(
      xb, wqb, wkb, wvb, bq, bk, bv, qhb, khb, vtb);
  attn_kernel<<<3200, 256, 0, stream>>>(qhb, khb, vtb, aw, scores, attnb);
  gemm_bt<0, 1, 1, 0><<<dim3(4, 100), 256, 0, stream>>>(
      attnb, wob, bo, x, ao, nullptr, 6400, 256, 256);
  ln_kernel<<<6400, 256, 0, stream>>>(ao, g1, be1, hbuf, hb);
  gemm_bt<1, 0, 0, 1><<<dim3(16, 100), 256, 0, stream>>>(
      hb, w1b, b1, nullptr, nullptr, ffn1b, 6400, 1024, 256);
  gemm_bt<0, 1, 1, 0><<<dim3(4, 100), 256, 0, stream>>>(
      ffn1b, w2b, b2, hbuf, ffn2, nullptr, 6400, 256, 1024);
  ln_kernel<<<6400, 256, 0, stream>>>(ffn2, g2, be2, yout, nullptr);
}